// Round 4
// baseline (704.672 us; speedup 1.0000x reference)
//
#include <hip/hip_runtime.h>
#include <stdint.h>

#define N_TOK 4096
#define C_DIM 256
#define NSPLIT 3

typedef __attribute__((ext_vector_type(8))) short short8;
typedef __attribute__((ext_vector_type(4))) float floatx4;
typedef __attribute__((ext_vector_type(4))) unsigned short ushort4v;

__device__ __forceinline__ unsigned short bf16_rne(float f) {
    union { float f; unsigned int u; } v; v.f = f;
    unsigned int u = v.u;
    unsigned int rounded = u + 0x7FFFu + ((u >> 16) & 1u);
    return (unsigned short)(rounded >> 16);
}
__device__ __forceinline__ float bf16_to_f(unsigned short h) {
    union { unsigned int u; float f; } v; v.u = ((unsigned int)h) << 16;
    return v.f;
}
// split f = hi + lo (both bf16) with combined error ~2^-18 relative
__device__ __forceinline__ void split_bf16(float f, unsigned short& h, unsigned short& l) {
    h = bf16_rne(f);
    l = bf16_rne(f - bf16_to_f(h));
}
// async global->LDS 16B/lane; LDS dest = wave-uniform base + lane*16
__device__ __forceinline__ void g2l16(const void* g, void* l) {
    __builtin_amdgcn_global_load_lds(
        (const __attribute__((address_space(1))) void*)g,
        (__attribute__((address_space(3))) void*)l, 16, 0, 0);
}
// select v[r] for r in 0..3 (cndmask chain, no LDS)
__device__ __forceinline__ float sel4(const float v[4], int r) {
    float x = v[0];
    x = (r == 1) ? v[1] : x;
    x = (r == 2) ? v[2] : x;
    x = (r == 3) ? v[3] : x;
    return x;
}

// ---------------------------------------------------------------------------
// prep_kernel: one-time split/transpose.
//  blocks 0..1023:  Xhi/Xlo[b][n][c] bf16 split of x (transposed via LDS)
//  blocks 1024..1026: Whi/Wlo[proj][o][c] bf16 split of Wq/Wk/Wv
// ---------------------------------------------------------------------------
__global__ __launch_bounds__(256) void prep_kernel(
    const float* __restrict__ x,
    const float* __restrict__ Wq, const float* __restrict__ Wk, const float* __restrict__ Wv,
    unsigned short* __restrict__ Xhi, unsigned short* __restrict__ Xlo,
    unsigned short* __restrict__ Whi, unsigned short* __restrict__ Wlo)
{
    const int t = threadIdx.x;
    if (blockIdx.x >= 1024) {
        const int pj = blockIdx.x - 1024;
        const float* W = (pj == 0) ? Wq : (pj == 1) ? Wk : Wv;
        unsigned short* dh = Whi + pj * 65536;
        unsigned short* dl = Wlo + pj * 65536;
        for (int it = 0; it < 64; it++) {
            const int idx = it * 1024 + t * 4;
            const float4 w = *(const float4*)&W[idx];
            unsigned short h0, l0, h1, l1, h2, l2, h3, l3;
            split_bf16(w.x, h0, l0); split_bf16(w.y, h1, l1);
            split_bf16(w.z, h2, l2); split_bf16(w.w, h3, l3);
            ushort4v vh; vh[0] = h0; vh[1] = h1; vh[2] = h2; vh[3] = h3;
            ushort4v vl; vl[0] = l0; vl[1] = l1; vl[2] = l2; vl[3] = l3;
            *(ushort4v*)&dh[idx] = vh;
            *(ushort4v*)&dl[idx] = vl;
        }
        return;
    }
    __shared__ float Xs[64 * 65];   // pitch 65: conflict-free transpose
    const int b  = blockIdx.x >> 8;
    const int ct = (blockIdx.x >> 6) & 3;
    const int nt = blockIdx.x & 63;
    const int c0 = ct * 64, n0 = nt * 64;
    {
        const int nch = t & 15, cr = t >> 4;
#pragma unroll
        for (int pass = 0; pass < 4; pass++) {
            const int c = pass * 16 + cr;
            const float4 v = *(const float4*)&x[((size_t)(b * C_DIM + c0 + c)) * N_TOK + n0 + nch * 4];
            float* row = &Xs[c * 65 + nch * 4];
            row[0] = v.x; row[1] = v.y; row[2] = v.z; row[3] = v.w;
        }
    }
    __syncthreads();
    {
        const int n = t >> 2, cc = t & 3;
        short8 vh0, vl0, vh1, vl1;
#pragma unroll
        for (int i = 0; i < 8; i++) {
            unsigned short h, l;
            split_bf16(Xs[(cc * 16 + i) * 65 + n], h, l);
            vh0[i] = (short)h; vl0[i] = (short)l;
        }
#pragma unroll
        for (int i = 0; i < 8; i++) {
            unsigned short h, l;
            split_bf16(Xs[(cc * 16 + 8 + i) * 65 + n], h, l);
            vh1[i] = (short)h; vl1[i] = (short)l;
        }
        const size_t off = ((size_t)b * N_TOK + n0 + n) * C_DIM + c0 + cc * 16;
        *(short8*)&Xhi[off] = vh0; *(short8*)&Xhi[off + 8] = vh1;
        *(short8*)&Xlo[off] = vl0; *(short8*)&Xlo[off + 8] = vl1;
    }
}

// ---------------------------------------------------------------------------
// proj_kernel: Out[n,o] = sum_c x[n,c]*W[o,c] + bias (+pos for K').
// Pure DMA-staged MFMA (pre-split inputs). 3-term for Q/K, 1-term for V.
// LDS 40KB -> 3 blocks/CU (grid 768).
// ---------------------------------------------------------------------------
__global__ __launch_bounds__(256) void proj_kernel(
    const unsigned short* __restrict__ Xhi, const unsigned short* __restrict__ Xlo,
    const unsigned short* __restrict__ Whi, const unsigned short* __restrict__ Wlo,
    const float* __restrict__ bq, const float* __restrict__ bk, const float* __restrict__ bv,
    const float* __restrict__ relh, const float* __restrict__ relw,
    float* __restrict__ Qf,
    unsigned short* __restrict__ Khi, unsigned short* __restrict__ Klo,
    unsigned short* __restrict__ Vg)
{
    __shared__ unsigned short SM[20480];   // 40KB carve
    unsigned short* Ah = SM;               // [64][32]
    unsigned short* Al = SM + 2048;
    unsigned short* Bh = SM + 4096;        // [256][32]
    unsigned short* Bl = SM + 12288;

    const int t    = threadIdx.x;
    const int wave = t >> 6;
    const int lane = t & 63;
    const int l15  = lane & 15;
    const int quad = lane >> 4;

    const int bp   = blockIdx.x >> 6;
    const int proj = bp % 3;
    const int b    = bp / 3;
    const int n0   = (blockIdx.x & 63) * 64;

    const unsigned short* Xh = Xhi + ((size_t)b * N_TOK + n0) * C_DIM;
    const unsigned short* Xl = Xlo + ((size_t)b * N_TOK + n0) * C_DIM;
    const unsigned short* Wh = Whi + proj * 65536;
    const unsigned short* Wl = Wlo + proj * 65536;
    const float* bias = (proj == 0) ? bq : (proj == 1) ? bk : bv;
    const bool needlo = (proj < 2);

    floatx4 acc[16];
#pragma unroll
    for (int i = 0; i < 16; i++) acc[i] = (floatx4){0.f, 0.f, 0.f, 0.f};

    for (int c0 = 0; c0 < 256; c0 += 32) {
        // ---- stage A (64 rows x 32c) + B (256 rows x 32c), XOR-chunk swizzle
        {
            const int lr = lane >> 2, cp = lane & 3;
            const int key = (lr ^ (lr >> 2)) & 3;
            const int r = wave * 16 + lr;
            g2l16(Xh + (size_t)r * C_DIM + c0 + (cp ^ key) * 8, &Ah[wave * 512]);
            if (needlo) g2l16(Xl + (size_t)r * C_DIM + c0 + (cp ^ key) * 8, &Al[wave * 512]);
#pragma unroll
            for (int p = 0; p < 4; p++) {
                const int rb = (p * 4 + wave) * 16;
                const int rr = rb + lr;
                g2l16(Wh + (size_t)rr * 256 + c0 + (cp ^ key) * 8, &Bh[rb * 32]);
                if (needlo) g2l16(Wl + (size_t)rr * 256 + c0 + (cp ^ key) * 8, &Bl[rb * 32]);
            }
        }
        __syncthreads();

        const int akey = (l15 ^ (l15 >> 2)) & 3;
        const int arow = (wave * 16 + l15) * 32 + ((quad ^ akey) * 8);
        const short8 a_h = *(const short8*)&Ah[arow];
        short8 a_l;
        if (needlo) a_l = *(const short8*)&Al[arow];
#pragma unroll
        for (int ot = 0; ot < 16; ot++) {
            const int brow = (ot * 16 + l15) * 32 + ((quad ^ akey) * 8);
            const short8 b_h = *(const short8*)&Bh[brow];
            acc[ot] = __builtin_amdgcn_mfma_f32_16x16x32_bf16(a_h, b_h, acc[ot], 0, 0, 0);
            if (needlo) {
                const short8 b_l = *(const short8*)&Bl[brow];
                acc[ot] = __builtin_amdgcn_mfma_f32_16x16x32_bf16(a_l, b_h, acc[ot], 0, 0, 0);
                acc[ot] = __builtin_amdgcn_mfma_f32_16x16x32_bf16(a_h, b_l, acc[ot], 0, 0, 0);
            }
        }
        __syncthreads();
    }

    // ---- epilogue ----
    const int h0 = n0 >> 6;   // pos[c][n] = relh[c][n>>6] + relw[c][n&63]
    if (proj == 0) {
        float* Og = Qf + ((size_t)b * N_TOK + n0) * C_DIM;
#pragma unroll
        for (int ot = 0; ot < 16; ot++) {
            const int o = ot * 16 + l15;
            const float bs = bias[o];
#pragma unroll
            for (int r = 0; r < 4; r++) {
                const int nl = wave * 16 + quad * 4 + r;
                Og[(size_t)nl * C_DIM + o] = acc[ot][r] + bs;
            }
        }
    } else if (proj == 1) {
        unsigned short* Oh = Khi + ((size_t)b * N_TOK + n0) * C_DIM;
        unsigned short* Ol = Klo + ((size_t)b * N_TOK + n0) * C_DIM;
#pragma unroll
        for (int ot = 0; ot < 16; ot++) {
            const int o = ot * 16 + l15;
            const float bs = bias[o];
            const float ph = relh[o * 64 + h0];
#pragma unroll
            for (int r = 0; r < 4; r++) {
                const int nl = wave * 16 + quad * 4 + r;
                const float val = acc[ot][r] + bs + ph + relw[o * 64 + nl];
                unsigned short h, l;
                split_bf16(val, h, l);
                Oh[(size_t)nl * C_DIM + o] = h;
                Ol[(size_t)nl * C_DIM + o] = l;
            }
        }
    } else {
        // V: bf16, transpose via LDS (reuse SM: 256x72 = 36KB <= 40KB)
        unsigned short* Vt = SM;
#pragma unroll
        for (int ot = 0; ot < 16; ot++) {
            const int o = ot * 16 + l15;
            const float bs = bias[o];
            const unsigned int u0 = (unsigned int)bf16_rne(acc[ot][0] + bs) |
                                    ((unsigned int)bf16_rne(acc[ot][1] + bs) << 16);
            const unsigned int u1 = (unsigned int)bf16_rne(acc[ot][2] + bs) |
                                    ((unsigned int)bf16_rne(acc[ot][3] + bs) << 16);
            uint2 uv; uv.x = u0; uv.y = u1;
            *(uint2*)&Vt[o * 72 + wave * 16 + quad * 4] = uv;
        }
        __syncthreads();
        const int ch   = t & 7;
        const int orow = t >> 3;
#pragma unroll
        for (int pass = 0; pass < 8; pass++) {
            const int o = pass * 32 + orow;
            const short8 vv = *(const short8*)&Vt[o * 72 + ch * 8];
            *(short8*)&Vg[((size_t)b * C_DIM + o) * N_TOK + n0 + ch * 8] = vv;
        }
    }
}

// ---------------------------------------------------------------------------
// flash_kernel (split-K x3, BN=32): block = (b, s third of j, 64-row q-tile).
// LDS 37KB; Pt per-wave (no barriers for P path); alpha/l via bpermute.
// Writes unnormalized O^T (bf16) + per-row (m,l).
// ---------------------------------------------------------------------------
__global__ __launch_bounds__(256, 3) void flash_kernel(
    const float* __restrict__ Qf,
    const unsigned short* __restrict__ Khi,
    const unsigned short* __restrict__ Klo,
    const unsigned short* __restrict__ Vg,
    unsigned short* __restrict__ Op,   // [NSPLIT][4][256][4096] bf16
    float* __restrict__ Lm)            // [NSPLIT][4][4096] float2 (m,l)
{
    __shared__ unsigned short KhiS[32 * 256];  // 16KB; reused as Vs [256][32]
    __shared__ unsigned short KloS[32 * 256];  // 16KB
    __shared__ unsigned short Pt[4 * 16 * 40]; // per-wave P^T [m][j], pitch 40
    unsigned short* Vs = KhiS;

    const int t    = threadIdx.x;
    const int wave = t >> 6;
    const int lane = t & 63;
    const int l15  = lane & 15;
    const int quad = lane >> 4;

    const int bid = blockIdx.x;                // 768 = 64 qt x 3 s x 4 b
    const int b   = bid & 3;
    const int s   = (bid >> 2) % 3;
    const int qt  = bid / 12;

    const float* Qb = Qf + (size_t)b * N_TOK * C_DIM;
    const unsigned short* Khb = Khi + (size_t)b * N_TOK * C_DIM;
    const unsigned short* Klb = Klo + (size_t)b * N_TOK * C_DIM;
    const unsigned short* Vb  = Vg  + (size_t)b * C_DIM * N_TOK;

    // Q fragments resident in registers (hi/lo split): 16 rows x 256c per wave
    short8 qh[8], ql[8];
    const int qrow = qt * 64 + wave * 16 + l15;
    {
        const float* Qrow = Qb + (size_t)qrow * C_DIM;
#pragma unroll
        for (int ct = 0; ct < 8; ct++) {
            const int base = ct * 32 + quad * 8;
            const float4 f0 = *(const float4*)&Qrow[base];
            const float4 f1 = *(const float4*)&Qrow[base + 4];
            short8 hh, ll;
            unsigned short h, l;
            split_bf16(f0.x, h, l); hh[0] = (short)h; ll[0] = (short)l;
            split_bf16(f0.y, h, l); hh[1] = (short)h; ll[1] = (short)l;
            split_bf16(f0.z, h, l); hh[2] = (short)h; ll[2] = (short)l;
            split_bf16(f0.w, h, l); hh[3] = (short)h; ll[3] = (short)l;
            split_bf16(f1.x, h, l); hh[4] = (short)h; ll[4] = (short)l;
            split_bf16(f1.y, h, l); hh[5] = (short)h; ll[5] = (short)l;
            split_bf16(f1.z, h, l); hh[6] = (short)h; ll[6] = (short)l;
            split_bf16(f1.w, h, l); hh[7] = (short)h; ll[7] = (short)l;
            qh[ct] = hh; ql[ct] = ll;
        }
    }

    floatx4 oacc[16];
#pragma unroll
    for (int i = 0; i < 16; i++) oacc[i] = (floatx4){0.f, 0.f, 0.f, 0.f};
    float m_i[4] = {-1e30f, -1e30f, -1e30f, -1e30f};
    float l_i[4] = {0.f, 0.f, 0.f, 0.f};

    unsigned short* Ptw = Pt + wave * 16 * 40;
    const int tstart = s * 43;
    const int ntiles = (s < 2) ? 43 : 42;
    const int bsrc = ((l15 >> 2) << 4) | (l15 & 3);   // bpermute src lane for row broadcast

    for (int nt = 0; nt < ntiles; nt++) {
        const int j0 = (tstart + nt) * 32;

        // ---- stage K' hi+lo [32][256] via DMA, chunk^(row&7) swizzle
        {
            const int lr = lane >> 5, cp = lane & 31;
#pragma unroll
            for (int p = 0; p < 4; p++) {
                const int rb = wave * 8 + p * 2;
                const int r  = rb + lr;
                const size_t go = (size_t)(j0 + r) * C_DIM + (cp ^ (r & 7)) * 8;
                g2l16(Khb + go, &KhiS[rb * 256]);
                g2l16(Klb + go, &KloS[rb * 256]);
            }
        }
        __syncthreads();

        // ---- S = Q K'^T (3-term split)
        floatx4 sv[2];
#pragma unroll
        for (int jt = 0; jt < 2; jt++) {
            floatx4 a = (floatx4){0.f, 0.f, 0.f, 0.f};
#pragma unroll
            for (int ct = 0; ct < 8; ct++) {
                const int cidx = (ct * 4 + quad) ^ (l15 & 7);
                const int off = (jt * 16 + l15) * 256 + cidx * 8;
                const short8 kh = *(const short8*)&KhiS[off];
                const short8 kl = *(const short8*)&KloS[off];
                a = __builtin_amdgcn_mfma_f32_16x16x32_bf16(qh[ct], kh, a, 0, 0, 0);
                a = __builtin_amdgcn_mfma_f32_16x16x32_bf16(ql[ct], kh, a, 0, 0, 0);
                a = __builtin_amdgcn_mfma_f32_16x16x32_bf16(qh[ct], kl, a, 0, 0, 0);
            }
            sv[jt] = a;
        }

        // ---- online softmax (16-lane row groups)
        float alpha[4];
#pragma unroll
        for (int r = 0; r < 4; r++) {
            float mx = fmaxf(sv[0][r], sv[1][r]);
            mx = fmaxf(mx, __shfl_xor(mx, 1));
            mx = fmaxf(mx, __shfl_xor(mx, 2));
            mx = fmaxf(mx, __shfl_xor(mx, 4));
            mx = fmaxf(mx, __shfl_xor(mx, 8));
            const float mn = fmaxf(m_i[r], mx);
            alpha[r] = __expf(m_i[r] - mn);
            m_i[r] = mn;
            const float p0 = __expf(sv[0][r] - mn);
            const float p1 = __expf(sv[1][r] - mn);
            sv[0][r] = p0; sv[1][r] = p1;
            float ps = p0 + p1;
            ps += __shfl_xor(ps, 1);
            ps += __shfl_xor(ps, 2);
            ps += __shfl_xor(ps, 4);
            ps += __shfl_xor(ps, 8);
            l_i[r] = l_i[r] * alpha[r] + ps;
        }

        // ---- P^T write [m][j] (per-wave region: no barrier needed)
#pragma unroll
        for (int jt = 0; jt < 2; jt++) {
#pragma unroll
            for (int r = 0; r < 4; r++)
                Ptw[(quad * 4 + r) * 40 + jt * 16 + l15] = bf16_rne(sv[jt][r]);
        }
        const float am = __shfl(sel4(alpha, l15 & 3), bsrc);
        const short8 pf = *(const short8*)&Ptw[l15 * 40 + quad * 8];
        __syncthreads();   // all waves' S-reads of KhiS/KloS done -> V may overwrite

        // ---- stage V [256][32] (overlaps rescale)
        {
            const int lr = lane >> 2, cp = lane & 3;
            const int key = (lr ^ (lr >> 2)) & 3;
#pragma unroll
            for (int p = 0; p < 4; p++) {
                const int rb = (p * 4 + wave) * 16;
                const int o  = rb + lr;
                g2l16(Vb + (size_t)o * N_TOK + j0 + (cp ^ key) * 8, &Vs[rb * 32]);
            }
        }
        if (__any(am != 1.0f)) {
#pragma unroll
            for (int ot = 0; ot < 16; ot++) {
                oacc[ot][0] *= am; oacc[ot][1] *= am; oacc[ot][2] *= am; oacc[ot][3] *= am;
            }
        }
        __syncthreads();   // V visible

        // ---- O^T += V P^T (1 MFMA per ot)
#pragma unroll
        for (int ot = 0; ot < 16; ot++) {
            const int vkey = (l15 ^ (l15 >> 2)) & 3;
            const short8 av = *(const short8*)&Vs[(ot * 16 + l15) * 32 + ((quad ^ vkey) * 8)];
            oacc[ot] = __builtin_amdgcn_mfma_f32_16x16x32_bf16(av, pf, oacc[ot], 0, 0, 0);
        }
        __syncthreads();   // protect Vs before next K stage
    }

    // ---- epilogue: unnormalized O^T bf16 + (m,l)
    unsigned short* Ob = Op + ((size_t)(s * 4 + b) * C_DIM) * N_TOK;
    const int n = qt * 64 + wave * 16 + l15;
#pragma unroll
    for (int ot = 0; ot < 16; ot++) {
#pragma unroll
        for (int r = 0; r < 4; r++) {
            const int c = ot * 16 + quad * 4 + r;
            Ob[(size_t)c * N_TOK + n] = bf16_rne(oacc[ot][r]);
        }
    }
    if (l15 == 0) {
        const size_t nb = (size_t)(s * 4 + b) * N_TOK + qt * 64 + wave * 16 + quad * 4;
#pragma unroll
        for (int r = 0; r < 4; r++)
            *(float2*)&Lm[(nb + r) * 2] = make_float2(m_i[r], l_i[r]);
    }
}

// ---------------------------------------------------------------------------
// merge_kernel: out = gamma * (sum_s w_s O_s) / (sum_s w_s l_s) + x
// ---------------------------------------------------------------------------
__global__ __launch_bounds__(256) void merge_kernel(
    const unsigned short* __restrict__ Op,
    const float* __restrict__ Lm,
    const float* __restrict__ x,
    const float* __restrict__ gamma,
    float* __restrict__ out)
{
    const int blk = blockIdx.x;          // 4096
    const int b   = blk >> 10;
    const int c   = (blk >> 2) & 255;
    const int nq  = blk & 3;
    const int n0  = nq * 1024 + threadIdx.x * 4;

    const size_t NEo = (size_t)4 * C_DIM * N_TOK;
    const size_t obase = ((size_t)b * C_DIM + c) * N_TOK + n0;

    float ms[NSPLIT][4], ls[NSPLIT][4], os[NSPLIT][4];
#pragma unroll
    for (int s = 0; s < NSPLIT; s++) {
        const uint2 u = *(const uint2*)&Op[s * NEo + obase];
        os[s][0] = bf16_to_f((unsigned short)(u.x & 0xffff));
        os[s][1] = bf16_to_f((unsigned short)(u.x >> 16));
        os[s][2] = bf16_to_f((unsigned short)(u.y & 0xffff));
        os[s][3] = bf16_to_f((unsigned short)(u.y >> 16));
        const float* Lms = Lm + (size_t)(s * 4 + b) * N_TOK * 2;
        const float4 A0 = *(const float4*)&Lms[n0 * 2];
        const float4 A1 = *(const float4*)&Lms[n0 * 2 + 4];
        ms[s][0] = A0.x; ls[s][0] = A0.y;
        ms[s][1] = A0.z; ls[s][1] = A0.w;
        ms[s][2] = A1.x; ls[s][2] = A1.y;
        ms[s][3] = A1.z; ls[s][3] = A1.w;
    }
    const float4 xv = *(const float4*)&x[obase];
    const float xin[4] = {xv.x, xv.y, xv.z, xv.w};
    const float g = gamma[0];

    float4 res;
    float* rp = (float*)&res;
#pragma unroll
    for (int i = 0; i < 4; i++) {
        float M = ms[0][i];
#pragma unroll
        for (int s = 1; s < NSPLIT; s++) M = fmaxf(M, ms[s][i]);
        float osum = 0.f, lsum = 0.f;
#pragma unroll
        for (int s = 0; s < NSPLIT; s++) {
            const float w = __expf(ms[s][i] - M);
            osum += w * os[s][i];
            lsum += w * ls[s][i];
        }
        rp[i] = g * osum / lsum + xin[i];
    }
    *(float4*)&out[obase] = res;
}

extern "C" void kernel_launch(void* const* d_in, const int* in_sizes, int n_in,
                              void* d_out, int out_size, void* d_ws, size_t ws_size,
                              hipStream_t stream) {
    const float* x     = (const float*)d_in[0];
    const float* Wq    = (const float*)d_in[1];
    const float* bq    = (const float*)d_in[2];
    const float* Wk    = (const float*)d_in[3];
    const float* bk    = (const float*)d_in[4];
    const float* Wv    = (const float*)d_in[5];
    const float* bv    = (const float*)d_in[6];
    const float* relh  = (const float*)d_in[7];
    const float* relw  = (const float*)d_in[8];
    const float* gamma = (const float*)d_in[9];
    float* out = (float*)d_out;

    const size_t NE = (size_t)4 * N_TOK * C_DIM;   // 4.19M elems

    // Region layout (Op overlays Xhi/Xlo: X dead before flash writes Op)
    unsigned short* Op  = (unsigned short*)d_ws;           // NSPLIT*NE shorts
    unsigned short* Xhi = Op;                              // NE shorts (prep/proj only)
    unsigned short* Xlo = Op + NE;                         // NE shorts
    unsigned short* Whi = Op + (size_t)NSPLIT * NE;        // 3*65536
    unsigned short* Wlo = Whi + 3 * 65536;
    float* Qf = (float*)(Wlo + 3 * 65536);                 // NE floats
    unsigned short* Khi = (unsigned short*)(Qf + NE);
    unsigned short* Klo = Khi + NE;
    unsigned short* Vg  = Klo + NE;
    float* Lm = (float*)(Vg + NE);                         // NSPLIT*4*4096*2 floats

    hipLaunchKernelGGL(prep_kernel, dim3(1027), dim3(256), 0, stream,
                       x, Wq, Wk, Wv, Xhi, Xlo, Whi, Wlo);
    hipLaunchKernelGGL(proj_kernel, dim3(768), dim3(256), 0, stream,
                       Xhi, Xlo, Whi, Wlo, bq, bk, bv, relh, relw, Qf, Khi, Klo, Vg);
    hipLaunchKernelGGL(flash_kernel, dim3(768), dim3(256), 0, stream,
                       Qf, Khi, Klo, Vg, Op, Lm);
    hipLaunchKernelGGL(merge_kernel, dim3(4096), dim3(256), 0, stream,
                       Op, Lm, x, gamma, out);
}

// Round 5
// 342.795 us; speedup vs baseline: 2.0557x; 2.0557x over previous
//
#include <hip/hip_runtime.h>
#include <stdint.h>

#define N_TOK 4096
#define C_DIM 256
#define NSPLIT 2

typedef __attribute__((ext_vector_type(8))) short short8;
typedef __attribute__((ext_vector_type(4))) float floatx4;
typedef __attribute__((ext_vector_type(4))) unsigned short ushort4v;

__device__ __forceinline__ unsigned short bf16_rne(float f) {
    union { float f; unsigned int u; } v; v.f = f;
    unsigned int u = v.u;
    unsigned int rounded = u + 0x7FFFu + ((u >> 16) & 1u);
    return (unsigned short)(rounded >> 16);
}
__device__ __forceinline__ float bf16_to_f(unsigned short h) {
    union { unsigned int u; float f; } v; v.u = ((unsigned int)h) << 16;
    return v.f;
}
// split f = hi + lo (both bf16) with combined error ~2^-18 relative
__device__ __forceinline__ void split_bf16(float f, unsigned short& h, unsigned short& l) {
    h = bf16_rne(f);
    l = bf16_rne(f - bf16_to_f(h));
}
// async global->LDS 16B/lane; LDS dest = wave-uniform base + lane*16
__device__ __forceinline__ void g2l16(const void* g, void* l) {
    __builtin_amdgcn_global_load_lds(
        (const __attribute__((address_space(1))) void*)g,
        (__attribute__((address_space(3))) void*)l, 16, 0, 0);
}
// select v[r] for r in 0..3 (cndmask chain, no LDS)
__device__ __forceinline__ float sel4(const float v[4], int r) {
    float x = v[0];
    x = (r == 1) ? v[1] : x;
    x = (r == 2) ? v[2] : x;
    x = (r == 3) ? v[3] : x;
    return x;
}

// ---------------------------------------------------------------------------
// prep_kernel: one-time split/transpose.
//  blocks 0..1023:  Xhi/Xlo[b][n][c] bf16 split of x (transposed via LDS)
//  blocks 1024..1026: Whi/Wlo[proj][o][c] bf16 split of Wq/Wk/Wv
// ---------------------------------------------------------------------------
__global__ __launch_bounds__(256) void prep_kernel(
    const float* __restrict__ x,
    const float* __restrict__ Wq, const float* __restrict__ Wk, const float* __restrict__ Wv,
    unsigned short* __restrict__ Xhi, unsigned short* __restrict__ Xlo,
    unsigned short* __restrict__ Whi, unsigned short* __restrict__ Wlo)
{
    const int t = threadIdx.x;
    if (blockIdx.x >= 1024) {
        const int pj = blockIdx.x - 1024;
        const float* W = (pj == 0) ? Wq : (pj == 1) ? Wk : Wv;
        unsigned short* dh = Whi + pj * 65536;
        unsigned short* dl = Wlo + pj * 65536;
        for (int it = 0; it < 64; it++) {
            const int idx = it * 1024 + t * 4;
            const float4 w = *(const float4*)&W[idx];
            unsigned short h0, l0, h1, l1, h2, l2, h3, l3;
            split_bf16(w.x, h0, l0); split_bf16(w.y, h1, l1);
            split_bf16(w.z, h2, l2); split_bf16(w.w, h3, l3);
            ushort4v vh; vh[0] = h0; vh[1] = h1; vh[2] = h2; vh[3] = h3;
            ushort4v vl; vl[0] = l0; vl[1] = l1; vl[2] = l2; vl[3] = l3;
            *(ushort4v*)&dh[idx] = vh;
            *(ushort4v*)&dl[idx] = vl;
        }
        return;
    }
    __shared__ float Xs[64 * 65];   // pitch 65: conflict-free transpose
    const int b  = blockIdx.x >> 8;
    const int ct = (blockIdx.x >> 6) & 3;
    const int nt = blockIdx.x & 63;
    const int c0 = ct * 64, n0 = nt * 64;
    {
        const int nch = t & 15, cr = t >> 4;
#pragma unroll
        for (int pass = 0; pass < 4; pass++) {
            const int c = pass * 16 + cr;
            const float4 v = *(const float4*)&x[((size_t)(b * C_DIM + c0 + c)) * N_TOK + n0 + nch * 4];
            float* row = &Xs[c * 65 + nch * 4];
            row[0] = v.x; row[1] = v.y; row[2] = v.z; row[3] = v.w;
        }
    }
    __syncthreads();
    {
        const int n = t >> 2, cc = t & 3;
        short8 vh0, vl0, vh1, vl1;
#pragma unroll
        for (int i = 0; i < 8; i++) {
            unsigned short h, l;
            split_bf16(Xs[(cc * 16 + i) * 65 + n], h, l);
            vh0[i] = (short)h; vl0[i] = (short)l;
        }
#pragma unroll
        for (int i = 0; i < 8; i++) {
            unsigned short h, l;
            split_bf16(Xs[(cc * 16 + 8 + i) * 65 + n], h, l);
            vh1[i] = (short)h; vl1[i] = (short)l;
        }
        const size_t off = ((size_t)b * N_TOK + n0 + n) * C_DIM + c0 + cc * 16;
        *(short8*)&Xhi[off] = vh0; *(short8*)&Xhi[off + 8] = vh1;
        *(short8*)&Xlo[off] = vl0; *(short8*)&Xlo[off + 8] = vl1;
    }
}

// ---------------------------------------------------------------------------
// proj_kernel: Out[n,o] = sum_c x[n,c]*W[o,c] + bias (+pos for K').
// Pure DMA-staged MFMA (pre-split inputs). 3-term for Q/K, 1-term for V.
// LDS 40KB -> 3 blocks/CU (grid 768).
// ---------------------------------------------------------------------------
__global__ __launch_bounds__(256) void proj_kernel(
    const unsigned short* __restrict__ Xhi, const unsigned short* __restrict__ Xlo,
    const unsigned short* __restrict__ Whi, const unsigned short* __restrict__ Wlo,
    const float* __restrict__ bq, const float* __restrict__ bk, const float* __restrict__ bv,
    const float* __restrict__ relh, const float* __restrict__ relw,
    float* __restrict__ Qf,
    unsigned short* __restrict__ Khi, unsigned short* __restrict__ Klo,
    unsigned short* __restrict__ Vg)
{
    __shared__ unsigned short SM[20480];   // 40KB carve
    unsigned short* Ah = SM;               // [64][32]
    unsigned short* Al = SM + 2048;
    unsigned short* Bh = SM + 4096;        // [256][32]
    unsigned short* Bl = SM + 12288;

    const int t    = threadIdx.x;
    const int wave = t >> 6;
    const int lane = t & 63;
    const int l15  = lane & 15;
    const int quad = lane >> 4;

    const int bp   = blockIdx.x >> 6;
    const int proj = bp % 3;
    const int b    = bp / 3;
    const int n0   = (blockIdx.x & 63) * 64;

    const unsigned short* Xh = Xhi + ((size_t)b * N_TOK + n0) * C_DIM;
    const unsigned short* Xl = Xlo + ((size_t)b * N_TOK + n0) * C_DIM;
    const unsigned short* Wh = Whi + proj * 65536;
    const unsigned short* Wl = Wlo + proj * 65536;
    const float* bias = (proj == 0) ? bq : (proj == 1) ? bk : bv;
    const bool needlo = (proj < 2);

    floatx4 acc[16];
#pragma unroll
    for (int i = 0; i < 16; i++) acc[i] = (floatx4){0.f, 0.f, 0.f, 0.f};

    for (int c0 = 0; c0 < 256; c0 += 32) {
        // ---- stage A (64 rows x 32c) + B (256 rows x 32c), XOR-chunk swizzle
        {
            const int lr = lane >> 2, cp = lane & 3;
            const int key = (lr ^ (lr >> 2)) & 3;
            const int r = wave * 16 + lr;
            g2l16(Xh + (size_t)r * C_DIM + c0 + (cp ^ key) * 8, &Ah[wave * 512]);
            if (needlo) g2l16(Xl + (size_t)r * C_DIM + c0 + (cp ^ key) * 8, &Al[wave * 512]);
#pragma unroll
            for (int p = 0; p < 4; p++) {
                const int rb = (p * 4 + wave) * 16;
                const int rr = rb + lr;
                g2l16(Wh + (size_t)rr * 256 + c0 + (cp ^ key) * 8, &Bh[rb * 32]);
                if (needlo) g2l16(Wl + (size_t)rr * 256 + c0 + (cp ^ key) * 8, &Bl[rb * 32]);
            }
        }
        __syncthreads();

        const int akey = (l15 ^ (l15 >> 2)) & 3;
        const int arow = (wave * 16 + l15) * 32 + ((quad ^ akey) * 8);
        const short8 a_h = *(const short8*)&Ah[arow];
        short8 a_l;
        if (needlo) a_l = *(const short8*)&Al[arow];
#pragma unroll
        for (int ot = 0; ot < 16; ot++) {
            const int brow = (ot * 16 + l15) * 32 + ((quad ^ akey) * 8);
            const short8 b_h = *(const short8*)&Bh[brow];
            acc[ot] = __builtin_amdgcn_mfma_f32_16x16x32_bf16(a_h, b_h, acc[ot], 0, 0, 0);
            if (needlo) {
                const short8 b_l = *(const short8*)&Bl[brow];
                acc[ot] = __builtin_amdgcn_mfma_f32_16x16x32_bf16(a_l, b_h, acc[ot], 0, 0, 0);
                acc[ot] = __builtin_amdgcn_mfma_f32_16x16x32_bf16(a_h, b_l, acc[ot], 0, 0, 0);
            }
        }
        __syncthreads();
    }

    // ---- epilogue ----
    const int h0 = n0 >> 6;   // pos[c][n] = relh[c][n>>6] + relw[c][n&63]
    if (proj == 0) {
        float* Og = Qf + ((size_t)b * N_TOK + n0) * C_DIM;
#pragma unroll
        for (int ot = 0; ot < 16; ot++) {
            const int o = ot * 16 + l15;
            const float bs = bias[o];
#pragma unroll
            for (int r = 0; r < 4; r++) {
                const int nl = wave * 16 + quad * 4 + r;
                Og[(size_t)nl * C_DIM + o] = acc[ot][r] + bs;
            }
        }
    } else if (proj == 1) {
        unsigned short* Oh = Khi + ((size_t)b * N_TOK + n0) * C_DIM;
        unsigned short* Ol = Klo + ((size_t)b * N_TOK + n0) * C_DIM;
#pragma unroll
        for (int ot = 0; ot < 16; ot++) {
            const int o = ot * 16 + l15;
            const float bs = bias[o];
            const float ph = relh[o * 64 + h0];
#pragma unroll
            for (int r = 0; r < 4; r++) {
                const int nl = wave * 16 + quad * 4 + r;
                const float val = acc[ot][r] + bs + ph + relw[o * 64 + nl];
                unsigned short h, l;
                split_bf16(val, h, l);
                Oh[(size_t)nl * C_DIM + o] = h;
                Ol[(size_t)nl * C_DIM + o] = l;
            }
        }
    } else {
        // V: bf16, transpose via LDS (reuse SM: 256x72 = 36KB <= 40KB)
        unsigned short* Vt = SM;
#pragma unroll
        for (int ot = 0; ot < 16; ot++) {
            const int o = ot * 16 + l15;
            const float bs = bias[o];
            const unsigned int u0 = (unsigned int)bf16_rne(acc[ot][0] + bs) |
                                    ((unsigned int)bf16_rne(acc[ot][1] + bs) << 16);
            const unsigned int u1 = (unsigned int)bf16_rne(acc[ot][2] + bs) |
                                    ((unsigned int)bf16_rne(acc[ot][3] + bs) << 16);
            uint2 uv; uv.x = u0; uv.y = u1;
            *(uint2*)&Vt[o * 72 + wave * 16 + quad * 4] = uv;
        }
        __syncthreads();
        const int ch   = t & 7;
        const int orow = t >> 3;
#pragma unroll
        for (int pass = 0; pass < 8; pass++) {
            const int o = pass * 32 + orow;
            const short8 vv = *(const short8*)&Vt[o * 72 + ch * 8];
            *(short8*)&Vg[((size_t)b * C_DIM + o) * N_TOK + n0 + ch * 8] = vv;
        }
    }
}

// ---------------------------------------------------------------------------
// flash_kernel (split-K x2, BN=64): block = (b, s, 64-row q-tile).
// CRITICAL: (b,s) == bid%8 so all blocks on one XCD share one 3MB K/V
// working set (fits 4MB L2). Period-12 mapping in R4 thrashed L2 (576us).
// Pt per-wave [m][j] -> PV B-frag is one ds_read_b128. 2 blocks/CU.
// ---------------------------------------------------------------------------
__global__ __launch_bounds__(256, 2) void flash_kernel(
    const float* __restrict__ Qf,
    const unsigned short* __restrict__ Khi,
    const unsigned short* __restrict__ Klo,
    const unsigned short* __restrict__ Vg,
    unsigned short* __restrict__ Op,   // [NSPLIT][4][256][4096] bf16
    float* __restrict__ Lm)            // [NSPLIT][4][4096] float2 (m,l)
{
    __shared__ unsigned short KhiS[64 * 256];  // 32KB; reused as Vs [256][64]
    __shared__ unsigned short KloS[64 * 256];  // 32KB
    __shared__ unsigned short Pt[4 * 16 * 72]; // per-wave P^T [m][j], pitch 72
    unsigned short* Vs = KhiS;

    const int t    = threadIdx.x;
    const int wave = t >> 6;
    const int lane = t & 63;
    const int l15  = lane & 15;
    const int quad = lane >> 4;
    const int lk   = l15 & 7;   // LDS chunk-swizzle key

    const int bid = blockIdx.x;
    const int b   = bid & 3;          // (b,s) = bid%8: XCD-affine working set
    const int s   = (bid >> 2) & 1;
    const int qt  = bid >> 3;         // 0..63

    const float* Qb = Qf + (size_t)b * N_TOK * C_DIM;
    const unsigned short* Khb = Khi + (size_t)b * N_TOK * C_DIM;
    const unsigned short* Klb = Klo + (size_t)b * N_TOK * C_DIM;
    const unsigned short* Vb  = Vg  + (size_t)b * C_DIM * N_TOK;

    // Q fragments resident in registers (hi/lo split): 16 rows x 256c per wave
    short8 qh[8], ql[8];
    const int qrow = qt * 64 + wave * 16 + l15;
    {
        const float* Qrow = Qb + (size_t)qrow * C_DIM;
#pragma unroll
        for (int ct = 0; ct < 8; ct++) {
            const int base = ct * 32 + quad * 8;
            const float4 f0 = *(const float4*)&Qrow[base];
            const float4 f1 = *(const float4*)&Qrow[base + 4];
            short8 hh, ll;
            unsigned short h, l;
            split_bf16(f0.x, h, l); hh[0] = (short)h; ll[0] = (short)l;
            split_bf16(f0.y, h, l); hh[1] = (short)h; ll[1] = (short)l;
            split_bf16(f0.z, h, l); hh[2] = (short)h; ll[2] = (short)l;
            split_bf16(f0.w, h, l); hh[3] = (short)h; ll[3] = (short)l;
            split_bf16(f1.x, h, l); hh[4] = (short)h; ll[4] = (short)l;
            split_bf16(f1.y, h, l); hh[5] = (short)h; ll[5] = (short)l;
            split_bf16(f1.z, h, l); hh[6] = (short)h; ll[6] = (short)l;
            split_bf16(f1.w, h, l); hh[7] = (short)h; ll[7] = (short)l;
            qh[ct] = hh; ql[ct] = ll;
        }
    }

    floatx4 oacc[16];
#pragma unroll
    for (int i = 0; i < 16; i++) oacc[i] = (floatx4){0.f, 0.f, 0.f, 0.f};
    float m_i[4] = {-1e30f, -1e30f, -1e30f, -1e30f};
    float l_i[4] = {0.f, 0.f, 0.f, 0.f};

    unsigned short* Ptw = Pt + wave * 16 * 72;
    const int jbase = s * 2048;
    const int bsrc = ((l15 >> 2) << 4) | (l15 & 3);   // shfl src for alpha[m=l15]

    for (int ti = 0; ti < 32; ti++) {
        const int j0 = jbase + ti * 64;

        // ---- stage K' hi+lo [64][256] via DMA; LDS chunk c' holds global c'^(row&7)
        {
            const int lr = lane >> 5;     // 0/1
            const int cp = lane & 31;     // 32 x 16B chunks per row
#pragma unroll
            for (int p = 0; p < 8; p++) {
                const int jl = wave * 16 + p * 2 + lr;
                const int g  = cp ^ (jl & 7);
                const size_t go = (size_t)(j0 + jl) * C_DIM + g * 8;
                g2l16(Khb + go, &KhiS[(wave * 16 + p * 2) * 256]);
                g2l16(Klb + go, &KloS[(wave * 16 + p * 2) * 256]);
            }
        }
        __syncthreads();

        // ---- S = Q K'^T (3-term split)
        floatx4 sv[4];
#pragma unroll
        for (int jt = 0; jt < 4; jt++) {
            floatx4 a = (floatx4){0.f, 0.f, 0.f, 0.f};
#pragma unroll
            for (int ct = 0; ct < 8; ct++) {
                const int cidx = (ct * 4 + quad) ^ lk;
                const int off = (jt * 16 + l15) * 256 + cidx * 8;
                const short8 kh = *(const short8*)&KhiS[off];
                const short8 kl = *(const short8*)&KloS[off];
                a = __builtin_amdgcn_mfma_f32_16x16x32_bf16(qh[ct], kh, a, 0, 0, 0);
                a = __builtin_amdgcn_mfma_f32_16x16x32_bf16(ql[ct], kh, a, 0, 0, 0);
                a = __builtin_amdgcn_mfma_f32_16x16x32_bf16(qh[ct], kl, a, 0, 0, 0);
            }
            sv[jt] = a;
        }

        // ---- online softmax (16-lane row groups)
        float alpha[4];
#pragma unroll
        for (int r = 0; r < 4; r++) {
            float mx = fmaxf(fmaxf(sv[0][r], sv[1][r]), fmaxf(sv[2][r], sv[3][r]));
            mx = fmaxf(mx, __shfl_xor(mx, 1));
            mx = fmaxf(mx, __shfl_xor(mx, 2));
            mx = fmaxf(mx, __shfl_xor(mx, 4));
            mx = fmaxf(mx, __shfl_xor(mx, 8));
            const float mn = fmaxf(m_i[r], mx);
            alpha[r] = __expf(m_i[r] - mn);
            m_i[r] = mn;
            float ps = 0.f;
#pragma unroll
            for (int jt = 0; jt < 4; jt++) {
                const float p = __expf(sv[jt][r] - mn);
                sv[jt][r] = p;
                ps += p;
            }
            ps += __shfl_xor(ps, 1);
            ps += __shfl_xor(ps, 2);
            ps += __shfl_xor(ps, 4);
            ps += __shfl_xor(ps, 8);
            l_i[r] = l_i[r] * alpha[r] + ps;
        }

        // ---- P^T write [m][j] (per-wave region; 16 u16 stores)
#pragma unroll
        for (int jt = 0; jt < 4; jt++) {
#pragma unroll
            for (int r = 0; r < 4; r++)
                Ptw[(quad * 4 + r) * 72 + jt * 16 + l15] = bf16_rne(sv[jt][r]);
        }
        const float am = __shfl(sel4(alpha, l15 & 3), bsrc);
        const short8 pf0 = *(const short8*)&Ptw[l15 * 72 + quad * 8];
        const short8 pf1 = *(const short8*)&Ptw[l15 * 72 + 32 + quad * 8];
        __syncthreads();   // K' fully consumed -> Vs may overwrite KhiS

        // ---- stage V [256][64] (async; overlaps rescale)
        {
            const int lr = lane >> 3;     // 0..7
            const int cp = lane & 7;      // 8 x 16B chunks per row
#pragma unroll
            for (int p = 0; p < 8; p++) {
                const int ob = (p * 4 + wave) * 8;
                const int o  = ob + lr;
                const int g  = cp ^ (o & 7);
                g2l16(Vb + (size_t)o * N_TOK + j0 + g * 8, &Vs[ob * 64]);
            }
        }
        if (__any(am != 1.0f)) {
#pragma unroll
            for (int ot = 0; ot < 16; ot++) {
                oacc[ot][0] *= am; oacc[ot][1] *= am; oacc[ot][2] *= am; oacc[ot][3] *= am;
            }
        }
        __syncthreads();   // V visible

        // ---- O^T += V P^T
#pragma unroll
        for (int ot = 0; ot < 16; ot++) {
            const int row = (ot * 16 + l15) * 64;
            const short8 av0 = *(const short8*)&Vs[row + (quad ^ lk) * 8];
            const short8 av1 = *(const short8*)&Vs[row + ((4 + quad) ^ lk) * 8];
            oacc[ot] = __builtin_amdgcn_mfma_f32_16x16x32_bf16(av0, pf0, oacc[ot], 0, 0, 0);
            oacc[ot] = __builtin_amdgcn_mfma_f32_16x16x32_bf16(av1, pf1, oacc[ot], 0, 0, 0);
        }
        __syncthreads();   // protect Vs before next K stage
    }

    // ---- epilogue: unnormalized O^T bf16 + (m,l)
    unsigned short* Ob = Op + ((size_t)(s * 4 + b) * C_DIM) * N_TOK;
    const int n = qt * 64 + wave * 16 + l15;
#pragma unroll
    for (int ot = 0; ot < 16; ot++) {
#pragma unroll
        for (int r = 0; r < 4; r++) {
            const int c = ot * 16 + quad * 4 + r;
            Ob[(size_t)c * N_TOK + n] = bf16_rne(oacc[ot][r]);
        }
    }
    if (l15 == 0) {
        const size_t nb = (size_t)(s * 4 + b) * N_TOK + qt * 64 + wave * 16 + quad * 4;
#pragma unroll
        for (int r = 0; r < 4; r++)
            *(float2*)&Lm[(nb + r) * 2] = make_float2(m_i[r], l_i[r]);
    }
}

// ---------------------------------------------------------------------------
// merge_kernel: out = gamma * (sum_s w_s O_s) / (sum_s w_s l_s) + x
// ---------------------------------------------------------------------------
__global__ __launch_bounds__(256) void merge_kernel(
    const unsigned short* __restrict__ Op,
    const float* __restrict__ Lm,
    const float* __restrict__ x,
    const float* __restrict__ gamma,
    float* __restrict__ out)
{
    const int blk = blockIdx.x;          // 4096
    const int b   = blk >> 10;
    const int c   = (blk >> 2) & 255;
    const int nq  = blk & 3;
    const int n0  = nq * 1024 + threadIdx.x * 4;

    const size_t NEo = (size_t)4 * C_DIM * N_TOK;
    const size_t obase = ((size_t)b * C_DIM + c) * N_TOK + n0;

    float ms[NSPLIT][4], ls[NSPLIT][4], os[NSPLIT][4];
#pragma unroll
    for (int s = 0; s < NSPLIT; s++) {
        const uint2 u = *(const uint2*)&Op[s * NEo + obase];
        os[s][0] = bf16_to_f((unsigned short)(u.x & 0xffff));
        os[s][1] = bf16_to_f((unsigned short)(u.x >> 16));
        os[s][2] = bf16_to_f((unsigned short)(u.y & 0xffff));
        os[s][3] = bf16_to_f((unsigned short)(u.y >> 16));
        const float* Lms = Lm + (size_t)(s * 4 + b) * N_TOK * 2;
        const float4 A0 = *(const float4*)&Lms[n0 * 2];
        const float4 A1 = *(const float4*)&Lms[n0 * 2 + 4];
        ms[s][0] = A0.x; ls[s][0] = A0.y;
        ms[s][1] = A0.z; ls[s][1] = A0.w;
        ms[s][2] = A1.x; ls[s][2] = A1.y;
        ms[s][3] = A1.z; ls[s][3] = A1.w;
    }
    const float4 xv = *(const float4*)&x[obase];
    const float xin[4] = {xv.x, xv.y, xv.z, xv.w};
    const float g = gamma[0];

    float4 res;
    float* rp = (float*)&res;
#pragma unroll
    for (int i = 0; i < 4; i++) {
        float M = ms[0][i];
#pragma unroll
        for (int s = 1; s < NSPLIT; s++) M = fmaxf(M, ms[s][i]);
        float osum = 0.f, lsum = 0.f;
#pragma unroll
        for (int s = 0; s < NSPLIT; s++) {
            const float w = __expf(ms[s][i] - M);
            osum += w * os[s][i];
            lsum += w * ls[s][i];
        }
        rp[i] = g * osum / lsum + xin[i];
    }
    *(float4*)&out[obase] = res;
}

extern "C" void kernel_launch(void* const* d_in, const int* in_sizes, int n_in,
                              void* d_out, int out_size, void* d_ws, size_t ws_size,
                              hipStream_t stream) {
    const float* x     = (const float*)d_in[0];
    const float* Wq    = (const float*)d_in[1];
    const float* bq    = (const float*)d_in[2];
    const float* Wk    = (const float*)d_in[3];
    const float* bk    = (const float*)d_in[4];
    const float* Wv    = (const float*)d_in[5];
    const float* bv    = (const float*)d_in[6];
    const float* relh  = (const float*)d_in[7];
    const float* relw  = (const float*)d_in[8];
    const float* gamma = (const float*)d_in[9];
    float* out = (float*)d_out;

    const size_t NE = (size_t)4 * N_TOK * C_DIM;   // 4.19M elems

    // Region layout (Op overlays Xhi/Xlo: X dead before flash writes Op)
    unsigned short* Op  = (unsigned short*)d_ws;           // NSPLIT*NE shorts
    unsigned short* Xhi = Op;                              // NE shorts (prep/proj only)
    unsigned short* Xlo = Op + NE;                         // NE shorts
    unsigned short* Whi = Op + (size_t)NSPLIT * NE;        // 3*65536
    unsigned short* Wlo = Whi + 3 * 65536;
    float* Qf = (float*)(Wlo + 3 * 65536);                 // NE floats
    unsigned short* Khi = (unsigned short*)(Qf + NE);
    unsigned short* Klo = Khi + NE;
    unsigned short* Vg  = Klo + NE;
    float* Lm = (float*)(Vg + NE);                         // NSPLIT*4*4096*2 floats

    hipLaunchKernelGGL(prep_kernel, dim3(1027), dim3(256), 0, stream,
                       x, Wq, Wk, Wv, Xhi, Xlo, Whi, Wlo);
    hipLaunchKernelGGL(proj_kernel, dim3(768), dim3(256), 0, stream,
                       Xhi, Xlo, Whi, Wlo, bq, bk, bv, relh, relw, Qf, Khi, Klo, Vg);
    hipLaunchKernelGGL(flash_kernel, dim3(512), dim3(256), 0, stream,
                       Qf, Khi, Klo, Vg, Op, Lm);
    hipLaunchKernelGGL(merge_kernel, dim3(4096), dim3(256), 0, stream,
                       Op, Lm, x, gamma, out);
}

// Round 6
// 263.419 us; speedup vs baseline: 2.6751x; 1.3013x over previous
//
#include <hip/hip_runtime.h>
#include <stdint.h>

#define N_TOK 4096
#define C_DIM 256
#define NSPLIT 2

typedef __attribute__((ext_vector_type(8))) short short8;
typedef __attribute__((ext_vector_type(8))) _Float16 half8;
typedef __attribute__((ext_vector_type(4))) float floatx4;
typedef __attribute__((ext_vector_type(4))) unsigned short ushort4v;

__device__ __forceinline__ unsigned short bf16_rne(float f) {
    union { float f; unsigned int u; } v; v.f = f;
    unsigned int u = v.u;
    unsigned int rounded = u + 0x7FFFu + ((u >> 16) & 1u);
    return (unsigned short)(rounded >> 16);
}
__device__ __forceinline__ float bf16_to_f(unsigned short h) {
    union { unsigned int u; float f; } v; v.u = ((unsigned int)h) << 16;
    return v.f;
}
__device__ __forceinline__ void split_bf16(float f, unsigned short& h, unsigned short& l) {
    h = bf16_rne(f);
    l = bf16_rne(f - bf16_to_f(h));
}
__device__ __forceinline__ unsigned short f2h(float f) {
    union { _Float16 h; unsigned short u; } v; v.h = (_Float16)f; return v.u;
}
__device__ __forceinline__ float h2f(unsigned short u) {
    union { unsigned short u; _Float16 h; } v; v.u = u; return (float)v.h;
}
// async global->LDS 16B/lane; LDS dest = wave-uniform base + lane*16
__device__ __forceinline__ void g2l16(const void* g, void* l) {
    __builtin_amdgcn_global_load_lds(
        (const __attribute__((address_space(1))) void*)g,
        (__attribute__((address_space(3))) void*)l, 16, 0, 0);
}

// ---------------------------------------------------------------------------
// prep_kernel: one-time split/transpose (bf16 hi/lo pairs for fp32-accurate
// projection GEMM).
//  blocks 0..1023:  Xhi/Xlo[b][n][c] of x (transposed via LDS)
//  blocks 1024..1026: Whi/Wlo[proj][o][c] of Wq/Wk/Wv
// ---------------------------------------------------------------------------
__global__ __launch_bounds__(256) void prep_kernel(
    const float* __restrict__ x,
    const float* __restrict__ Wq, const float* __restrict__ Wk, const float* __restrict__ Wv,
    unsigned short* __restrict__ Xhi, unsigned short* __restrict__ Xlo,
    unsigned short* __restrict__ Whi, unsigned short* __restrict__ Wlo)
{
    const int t = threadIdx.x;
    if (blockIdx.x >= 1024) {
        const int pj = blockIdx.x - 1024;
        const float* W = (pj == 0) ? Wq : (pj == 1) ? Wk : Wv;
        unsigned short* dh = Whi + pj * 65536;
        unsigned short* dl = Wlo + pj * 65536;
        for (int it = 0; it < 64; it++) {
            const int idx = it * 1024 + t * 4;
            const float4 w = *(const float4*)&W[idx];
            unsigned short h0, l0, h1, l1, h2, l2, h3, l3;
            split_bf16(w.x, h0, l0); split_bf16(w.y, h1, l1);
            split_bf16(w.z, h2, l2); split_bf16(w.w, h3, l3);
            ushort4v vh; vh[0] = h0; vh[1] = h1; vh[2] = h2; vh[3] = h3;
            ushort4v vl; vl[0] = l0; vl[1] = l1; vl[2] = l2; vl[3] = l3;
            *(ushort4v*)&dh[idx] = vh;
            *(ushort4v*)&dl[idx] = vl;
        }
        return;
    }
    __shared__ float Xs[64 * 65];   // pitch 65: conflict-free transpose
    const int b  = blockIdx.x >> 8;
    const int ct = (blockIdx.x >> 6) & 3;
    const int nt = blockIdx.x & 63;
    const int c0 = ct * 64, n0 = nt * 64;
    {
        const int nch = t & 15, cr = t >> 4;
#pragma unroll
        for (int pass = 0; pass < 4; pass++) {
            const int c = pass * 16 + cr;
            const float4 v = *(const float4*)&x[((size_t)(b * C_DIM + c0 + c)) * N_TOK + n0 + nch * 4];
            float* row = &Xs[c * 65 + nch * 4];
            row[0] = v.x; row[1] = v.y; row[2] = v.z; row[3] = v.w;
        }
    }
    __syncthreads();
    {
        const int n = t >> 2, cc = t & 3;
        short8 vh0, vl0, vh1, vl1;
#pragma unroll
        for (int i = 0; i < 8; i++) {
            unsigned short h, l;
            split_bf16(Xs[(cc * 16 + i) * 65 + n], h, l);
            vh0[i] = (short)h; vl0[i] = (short)l;
        }
#pragma unroll
        for (int i = 0; i < 8; i++) {
            unsigned short h, l;
            split_bf16(Xs[(cc * 16 + 8 + i) * 65 + n], h, l);
            vh1[i] = (short)h; vl1[i] = (short)l;
        }
        const size_t off = ((size_t)b * N_TOK + n0 + n) * C_DIM + c0 + cc * 16;
        *(short8*)&Xhi[off] = vh0; *(short8*)&Xhi[off + 8] = vh1;
        *(short8*)&Xlo[off] = vl0; *(short8*)&Xlo[off + 8] = vl1;
    }
}

// ---------------------------------------------------------------------------
// proj_kernel: Out[n,o] = sum_c x[n,c]*W[o,c] + bias (+pos for K').
// Split-bf16 3-term MFMA internally (~fp32 accuracy); outputs all fp16:
//   Qh[b][n][o], Kh[b][n][o] (k+pos), Vh[b][o][n]
// ---------------------------------------------------------------------------
__global__ __launch_bounds__(256) void proj_kernel(
    const unsigned short* __restrict__ Xhi, const unsigned short* __restrict__ Xlo,
    const unsigned short* __restrict__ Whi, const unsigned short* __restrict__ Wlo,
    const float* __restrict__ bq, const float* __restrict__ bk, const float* __restrict__ bv,
    const float* __restrict__ relh, const float* __restrict__ relw,
    unsigned short* __restrict__ Qh,
    unsigned short* __restrict__ Kh,
    unsigned short* __restrict__ Vh)
{
    __shared__ unsigned short SM[20480];   // 40KB carve
    unsigned short* Ah = SM;               // [64][32]
    unsigned short* Al = SM + 2048;
    unsigned short* Bh = SM + 4096;        // [256][32]
    unsigned short* Bl = SM + 12288;

    const int t    = threadIdx.x;
    const int wave = t >> 6;
    const int lane = t & 63;
    const int l15  = lane & 15;
    const int quad = lane >> 4;

    const int bp   = blockIdx.x >> 6;
    const int proj = bp % 3;
    const int b    = bp / 3;
    const int n0   = (blockIdx.x & 63) * 64;

    const unsigned short* Xh = Xhi + ((size_t)b * N_TOK + n0) * C_DIM;
    const unsigned short* Xl = Xlo + ((size_t)b * N_TOK + n0) * C_DIM;
    const unsigned short* Wh = Whi + proj * 65536;
    const unsigned short* Wl = Wlo + proj * 65536;
    const float* bias = (proj == 0) ? bq : (proj == 1) ? bk : bv;
    const bool needlo = (proj < 2);

    floatx4 acc[16];
#pragma unroll
    for (int i = 0; i < 16; i++) acc[i] = (floatx4){0.f, 0.f, 0.f, 0.f};

    for (int c0 = 0; c0 < 256; c0 += 32) {
        {
            const int lr = lane >> 2, cp = lane & 3;
            const int key = (lr ^ (lr >> 2)) & 3;
            const int r = wave * 16 + lr;
            g2l16(Xh + (size_t)r * C_DIM + c0 + (cp ^ key) * 8, &Ah[wave * 512]);
            if (needlo) g2l16(Xl + (size_t)r * C_DIM + c0 + (cp ^ key) * 8, &Al[wave * 512]);
#pragma unroll
            for (int p = 0; p < 4; p++) {
                const int rb = (p * 4 + wave) * 16;
                const int rr = rb + lr;
                g2l16(Wh + (size_t)rr * 256 + c0 + (cp ^ key) * 8, &Bh[rb * 32]);
                if (needlo) g2l16(Wl + (size_t)rr * 256 + c0 + (cp ^ key) * 8, &Bl[rb * 32]);
            }
        }
        __syncthreads();

        const int akey = (l15 ^ (l15 >> 2)) & 3;
        const int arow = (wave * 16 + l15) * 32 + ((quad ^ akey) * 8);
        const short8 a_h = *(const short8*)&Ah[arow];
        short8 a_l;
        if (needlo) a_l = *(const short8*)&Al[arow];
#pragma unroll
        for (int ot = 0; ot < 16; ot++) {
            const int brow = (ot * 16 + l15) * 32 + ((quad ^ akey) * 8);
            const short8 b_h = *(const short8*)&Bh[brow];
            acc[ot] = __builtin_amdgcn_mfma_f32_16x16x32_bf16(a_h, b_h, acc[ot], 0, 0, 0);
            if (needlo) {
                const short8 b_l = *(const short8*)&Bl[brow];
                acc[ot] = __builtin_amdgcn_mfma_f32_16x16x32_bf16(a_l, b_h, acc[ot], 0, 0, 0);
                acc[ot] = __builtin_amdgcn_mfma_f32_16x16x32_bf16(a_h, b_l, acc[ot], 0, 0, 0);
            }
        }
        __syncthreads();
    }

    // ---- epilogue (all fp16 outputs) ----
    const int h0 = n0 >> 6;   // pos[c][n] = relh[c][n>>6] + relw[c][n&63]
    if (proj == 0) {
        unsigned short* Og = Qh + ((size_t)b * N_TOK + n0) * C_DIM;
#pragma unroll
        for (int ot = 0; ot < 16; ot++) {
            const int o = ot * 16 + l15;
            const float bs = bias[o];
#pragma unroll
            for (int r = 0; r < 4; r++) {
                const int nl = wave * 16 + quad * 4 + r;
                Og[(size_t)nl * C_DIM + o] = f2h(acc[ot][r] + bs);
            }
        }
    } else if (proj == 1) {
        unsigned short* Og = Kh + ((size_t)b * N_TOK + n0) * C_DIM;
#pragma unroll
        for (int ot = 0; ot < 16; ot++) {
            const int o = ot * 16 + l15;
            const float bs = bias[o];
            const float ph = relh[o * 64 + h0];
#pragma unroll
            for (int r = 0; r < 4; r++) {
                const int nl = wave * 16 + quad * 4 + r;
                Og[(size_t)nl * C_DIM + o] = f2h(acc[ot][r] + bs + ph + relw[o * 64 + nl]);
            }
        }
    } else {
        // V: fp16, transpose via LDS (reuse SM: 256x72 shorts = 36KB)
        unsigned short* Vt = SM;
#pragma unroll
        for (int ot = 0; ot < 16; ot++) {
            const int o = ot * 16 + l15;
            const float bs = bias[o];
            const unsigned int u0 = (unsigned int)f2h(acc[ot][0] + bs) |
                                    ((unsigned int)f2h(acc[ot][1] + bs) << 16);
            const unsigned int u1 = (unsigned int)f2h(acc[ot][2] + bs) |
                                    ((unsigned int)f2h(acc[ot][3] + bs) << 16);
            uint2 uv; uv.x = u0; uv.y = u1;
            *(uint2*)&Vt[o * 72 + wave * 16 + quad * 4] = uv;
        }
        __syncthreads();
        const int ch   = t & 7;
        const int orow = t >> 3;
#pragma unroll
        for (int pass = 0; pass < 8; pass++) {
            const int o = pass * 32 + orow;
            const short8 vv = *(const short8*)&Vt[o * 72 + ch * 8];
            *(short8*)&Vh[((size_t)b * C_DIM + o) * N_TOK + n0 + ch * 8] = vv;
        }
    }
}

// ---------------------------------------------------------------------------
// flash_kernel (split-K x2, BN=64, fp16 single-term): block = (b,s,qt).
// (b,s) == bid%8: XCD-affine working set (~2MB/XCD, fits 4MB L2).
// Disjoint K/V LDS buffers -> V-DMA flies under S-MFMAs, K(t+1)-DMA flies
// under PV-MFMAs; the vmcnt(0) at each barrier drains exactly the needed DMA.
// ---------------------------------------------------------------------------
__global__ __launch_bounds__(256, 2) void flash_kernel(
    const unsigned short* __restrict__ Qg,   // fp16 [4][4096][256]
    const unsigned short* __restrict__ Kg,   // fp16 [4][4096][256] (k+pos)
    const unsigned short* __restrict__ Vg,   // fp16 [4][256][4096]
    unsigned short* __restrict__ Op,         // fp16 [NSPLIT][4][256][4096]
    float* __restrict__ Lm)                  // [NSPLIT][4][4096] float2 (m,l)
{
    __shared__ unsigned short Ks[64 * 256];   // 32KB  K' tile [j][c]
    __shared__ unsigned short Vs[256 * 64];   // 32KB  V tile [c][j]
    __shared__ unsigned short Pt[4 * 16 * 72];// 9KB   per-wave P^T [m][j]
    __shared__ float abuf[4][16];

    const int t    = threadIdx.x;
    const int wave = t >> 6;
    const int lane = t & 63;
    const int l15  = lane & 15;
    const int quad = lane >> 4;
    const int lk   = l15 & 7;   // LDS chunk-swizzle key

    const int bid = blockIdx.x;
    const int b   = bid & 3;
    const int s   = (bid >> 2) & 1;
    const int qt  = bid >> 3;         // 0..63

    const unsigned short* Kb = Kg + (size_t)b * N_TOK * C_DIM;
    const unsigned short* Vb = Vg + (size_t)b * C_DIM * N_TOK;

    // Q fragments (fp16) resident in registers: 16 rows x 256c per wave
    half8 qf[8];
    const int qrow = qt * 64 + wave * 16 + l15;
    {
        const unsigned short* Qrow = Qg + ((size_t)b * N_TOK + qrow) * C_DIM;
#pragma unroll
        for (int ct = 0; ct < 8; ct++)
            qf[ct] = *(const half8*)&Qrow[ct * 32 + quad * 8];
    }

    floatx4 oacc[16];
#pragma unroll
    for (int i = 0; i < 16; i++) oacc[i] = (floatx4){0.f, 0.f, 0.f, 0.f};
    float m_i[4] = {-1e30f, -1e30f, -1e30f, -1e30f};
    float l_i[4] = {0.f, 0.f, 0.f, 0.f};

    unsigned short* Ptw = Pt + wave * 16 * 72;
    const int jbase = s * 2048;

    // ---- preamble: stage K tile 0
    {
        const int lr = lane >> 5, cp = lane & 31;
#pragma unroll
        for (int p = 0; p < 8; p++) {
            const int jl = wave * 16 + p * 2 + lr;
            g2l16(Kb + (size_t)(jbase + jl) * C_DIM + (cp ^ (jl & 7)) * 8,
                  &Ks[(wave * 16 + p * 2) * 256]);
        }
    }

    for (int ti = 0; ti < 32; ti++) {
        const int j0 = jbase + ti * 64;

        __syncthreads();   // B1: K(ti) visible (vmcnt drained); PV(ti-1) V-reads done

        // ---- stage V(ti) async (flies under S-MFMAs)
        {
            const int lr = lane >> 3, cp = lane & 7;
#pragma unroll
            for (int p = 0; p < 8; p++) {
                const int ob = (p * 4 + wave) * 8;
                const int o  = ob + lr;
                g2l16(Vb + (size_t)o * N_TOK + j0 + (cp ^ (o & 7)) * 8, &Vs[ob * 64]);
            }
        }

        // ---- S = Q K'^T (single-term fp16)
        floatx4 sv[4];
#pragma unroll
        for (int jt = 0; jt < 4; jt++) {
            floatx4 a = (floatx4){0.f, 0.f, 0.f, 0.f};
#pragma unroll
            for (int ct = 0; ct < 8; ct++) {
                const half8 kb = *(const half8*)&Ks[(jt * 16 + l15) * 256 + (((ct * 4 + quad) ^ lk) * 8)];
                a = __builtin_amdgcn_mfma_f32_16x16x32_f16(qf[ct], kb, a, 0, 0, 0);
            }
            sv[jt] = a;
        }

        // ---- online softmax (16-lane row groups)
        float alpha[4];
#pragma unroll
        for (int r = 0; r < 4; r++) {
            float mx = fmaxf(fmaxf(sv[0][r], sv[1][r]), fmaxf(sv[2][r], sv[3][r]));
            mx = fmaxf(mx, __shfl_xor(mx, 1));
            mx = fmaxf(mx, __shfl_xor(mx, 2));
            mx = fmaxf(mx, __shfl_xor(mx, 4));
            mx = fmaxf(mx, __shfl_xor(mx, 8));
            const float mn = fmaxf(m_i[r], mx);
            alpha[r] = __expf(m_i[r] - mn);
            m_i[r] = mn;
            float ps = 0.f;
#pragma unroll
            for (int jt = 0; jt < 4; jt++) {
                const float p = __expf(sv[jt][r] - mn);
                sv[jt][r] = p;
                ps += p;
            }
            ps += __shfl_xor(ps, 1);
            ps += __shfl_xor(ps, 2);
            ps += __shfl_xor(ps, 4);
            ps += __shfl_xor(ps, 8);
            l_i[r] = l_i[r] * alpha[r] + ps;
        }

        // ---- P^T [m][j] fp16 + alpha broadcast (per-wave LDS: no barrier dep)
#pragma unroll
        for (int jt = 0; jt < 4; jt++) {
#pragma unroll
            for (int r = 0; r < 4; r++)
                Ptw[(quad * 4 + r) * 72 + jt * 16 + l15] = f2h(sv[jt][r]);
        }
        if (l15 == 0)
            *(float4*)&abuf[wave][quad * 4] = make_float4(alpha[0], alpha[1], alpha[2], alpha[3]);
        const half8 pf0 = *(const half8*)&Ptw[l15 * 72 + quad * 8];
        const half8 pf1 = *(const half8*)&Ptw[l15 * 72 + 32 + quad * 8];
        const float am = abuf[wave][l15];
#pragma unroll
        for (int ot = 0; ot < 16; ot++) {
            oacc[ot][0] *= am; oacc[ot][1] *= am; oacc[ot][2] *= am; oacc[ot][3] *= am;
        }

        __syncthreads();   // B2: V(ti) visible; all waves done reading K(ti)

        // ---- stage K(ti+1) async (flies under PV-MFMAs)
        if (ti < 31) {
            const int lr = lane >> 5, cp = lane & 31;
#pragma unroll
            for (int p = 0; p < 8; p++) {
                const int jl = wave * 16 + p * 2 + lr;
                g2l16(Kb + (size_t)(j0 + 64 + jl) * C_DIM + (cp ^ (jl & 7)) * 8,
                      &Ks[(wave * 16 + p * 2) * 256]);
            }
        }

        // ---- O^T += V P^T
#pragma unroll
        for (int ot = 0; ot < 16; ot++) {
            const int row = (ot * 16 + l15) * 64;
            const half8 av0 = *(const half8*)&Vs[row + ((quad ^ lk) * 8)];
            const half8 av1 = *(const half8*)&Vs[row + (((4 + quad) ^ lk) * 8)];
            oacc[ot] = __builtin_amdgcn_mfma_f32_16x16x32_f16(av0, pf0, oacc[ot], 0, 0, 0);
            oacc[ot] = __builtin_amdgcn_mfma_f32_16x16x32_f16(av1, pf1, oacc[ot], 0, 0, 0);
        }
    }

    // ---- epilogue: unnormalized O^T fp16 + (m,l)
    unsigned short* Ob = Op + ((size_t)(s * 4 + b) * C_DIM) * N_TOK;
    const int n = qt * 64 + wave * 16 + l15;
#pragma unroll
    for (int ot = 0; ot < 16; ot++) {
#pragma unroll
        for (int r = 0; r < 4; r++) {
            const int c = ot * 16 + quad * 4 + r;
            Ob[(size_t)c * N_TOK + n] = f2h(oacc[ot][r]);
        }
    }
    if (l15 == 0) {
        const size_t nb = (size_t)(s * 4 + b) * N_TOK + qt * 64 + wave * 16 + quad * 4;
#pragma unroll
        for (int r = 0; r < 4; r++)
            *(float2*)&Lm[(nb + r) * 2] = make_float2(m_i[r], l_i[r]);
    }
}

// ---------------------------------------------------------------------------
// merge_kernel: out = gamma * (sum_s w_s O_s) / (sum_s w_s l_s) + x
// ---------------------------------------------------------------------------
__global__ __launch_bounds__(256) void merge_kernel(
    const unsigned short* __restrict__ Op,
    const float* __restrict__ Lm,
    const float* __restrict__ x,
    const float* __restrict__ gamma,
    float* __restrict__ out)
{
    const int blk = blockIdx.x;          // 4096
    const int b   = blk >> 10;
    const int c   = (blk >> 2) & 255;
    const int nq  = blk & 3;
    const int n0  = nq * 1024 + threadIdx.x * 4;

    const size_t NEo = (size_t)4 * C_DIM * N_TOK;
    const size_t obase = ((size_t)b * C_DIM + c) * N_TOK + n0;

    float ms[NSPLIT][4], ls[NSPLIT][4], os[NSPLIT][4];
#pragma unroll
    for (int s = 0; s < NSPLIT; s++) {
        const uint2 u = *(const uint2*)&Op[s * NEo + obase];
        os[s][0] = h2f((unsigned short)(u.x & 0xffff));
        os[s][1] = h2f((unsigned short)(u.x >> 16));
        os[s][2] = h2f((unsigned short)(u.y & 0xffff));
        os[s][3] = h2f((unsigned short)(u.y >> 16));
        const float* Lms = Lm + (size_t)(s * 4 + b) * N_TOK * 2;
        const float4 A0 = *(const float4*)&Lms[n0 * 2];
        const float4 A1 = *(const float4*)&Lms[n0 * 2 + 4];
        ms[s][0] = A0.x; ls[s][0] = A0.y;
        ms[s][1] = A0.z; ls[s][1] = A0.w;
        ms[s][2] = A1.x; ls[s][2] = A1.y;
        ms[s][3] = A1.z; ls[s][3] = A1.w;
    }
    const float4 xv = *(const float4*)&x[obase];
    const float xin[4] = {xv.x, xv.y, xv.z, xv.w};
    const float g = gamma[0];

    float4 res;
    float* rp = (float*)&res;
#pragma unroll
    for (int i = 0; i < 4; i++) {
        float M = ms[0][i];
#pragma unroll
        for (int s = 1; s < NSPLIT; s++) M = fmaxf(M, ms[s][i]);
        float osum = 0.f, lsum = 0.f;
#pragma unroll
        for (int s = 0; s < NSPLIT; s++) {
            const float w = __expf(ms[s][i] - M);
            osum += w * os[s][i];
            lsum += w * ls[s][i];
        }
        rp[i] = g * osum / lsum + xin[i];
    }
    *(float4*)&out[obase] = res;
}

extern "C" void kernel_launch(void* const* d_in, const int* in_sizes, int n_in,
                              void* d_out, int out_size, void* d_ws, size_t ws_size,
                              hipStream_t stream) {
    const float* x     = (const float*)d_in[0];
    const float* Wq    = (const float*)d_in[1];
    const float* bq    = (const float*)d_in[2];
    const float* Wk    = (const float*)d_in[3];
    const float* bk    = (const float*)d_in[4];
    const float* Wv    = (const float*)d_in[5];
    const float* bv    = (const float*)d_in[6];
    const float* relh  = (const float*)d_in[7];
    const float* relw  = (const float*)d_in[8];
    const float* gamma = (const float*)d_in[9];
    float* out = (float*)d_out;

    const size_t NE = (size_t)4 * N_TOK * C_DIM;   // 4.19M elems

    // Region layout (Op overlays Xhi/Xlo: X dead before flash writes Op)
    unsigned short* Op  = (unsigned short*)d_ws;           // NSPLIT*NE u16
    unsigned short* Xhi = Op;                              // NE u16 (prep/proj only)
    unsigned short* Xlo = Op + NE;                         // NE u16
    unsigned short* Whi = Op + (size_t)NSPLIT * NE;        // 3*65536 u16
    unsigned short* Wlo = Whi + 3 * 65536;
    unsigned short* Qh  = Wlo + 3 * 65536;                 // NE u16 (fp16)
    unsigned short* Kh  = Qh + NE;                         // NE u16 (fp16)
    unsigned short* Vh  = Kh + NE;                         // NE u16 (fp16)
    float* Lm = (float*)(Vh + NE);                         // NSPLIT*4*4096*2 floats

    hipLaunchKernelGGL(prep_kernel, dim3(1027), dim3(256), 0, stream,
                       x, Wq, Wk, Wv, Xhi, Xlo, Whi, Wlo);
    hipLaunchKernelGGL(proj_kernel, dim3(768), dim3(256), 0, stream,
                       Xhi, Xlo, Whi, Wlo, bq, bk, bv, relh, relw, Qh, Kh, Vh);
    hipLaunchKernelGGL(flash_kernel, dim3(512), dim3(256), 0, stream,
                       Qh, Kh, Vh, Op, Lm);
    hipLaunchKernelGGL(merge_kernel, dim3(4096), dim3(256), 0, stream,
                       Op, Lm, x, gamma, out);
}